// Round 6
// baseline (140.648 us; speedup 1.0000x reference)
//
#include <hip/hip_runtime.h>
#include <cstdint>
#include <cstddef>

#define N_NODES 50000
#define N_EDGES 800000
#define CAP 64        // max in-degree capacity; Poisson(16): P(>64) astronomically small

// XCD-sharded build geometry
#define SHARDS 8
#define SHARD_SZ 6250                 // N_NODES / SHARDS
#define CHUNK_EDGES 8192              // 256 thr * 4 edges * 8 iters
#define N_CHUNKS 98                   // ceil(800000 / 8192)
#define NB_BUILD (N_CHUNKS * SHARDS)  // 784

// K0 (pre) block ranges: zero cnt | pack W | combine
#define NB_ZERO 49                    // 49 * 1024 ints >= 50000
#define NB_PACK 128
#define NB_COMB 2
#define NB_PRE  (NB_ZERO + NB_PACK + NB_COMB)

// K1 (main) = build blocks then gemm blocks
#define NB_GEMM 782                   // ceil(50000/64)
#define NB_MAIN (NB_BUILD + NB_GEMM)

// K2/K3 node remap: 1563 blocks per shard (4 nodes per block)
#define NB_AGG (1563 * 8)

typedef __attribute__((ext_vector_type(8))) short bf16x8;   // MFMA A/B frag (4 VGPRs)
typedef __attribute__((ext_vector_type(4))) float f32x4;    // MFMA C/D frag

__device__ __forceinline__ unsigned short f2bf(float f) {
    unsigned u = __builtin_bit_cast(unsigned, f);
    u += 0x7fff + ((u >> 16) & 1);          // round-to-nearest-even
    return (unsigned short)(u >> 16);
}
__device__ __forceinline__ float bflo(unsigned u) { return __builtin_bit_cast(float, u << 16); }
__device__ __forceinline__ float bfhi(unsigned u) { return __builtin_bit_cast(float, u & 0xffff0000u); }

// ---------------- K0: zero cnt | pack [W1s;W1n] -> bf16 frags | fold W2*@Wf ----------------
__global__ __launch_bounds__(256) void k_pre(const float* __restrict__ W1s,
                                             const float* __restrict__ W1n,
                                             const float* __restrict__ W2s,
                                             const float* __restrict__ W2n,
                                             const float* __restrict__ b2,
                                             const float* __restrict__ Wf,
                                             const float* __restrict__ bf,
                                             int* __restrict__ cnt,
                                             unsigned short* __restrict__ wpack,
                                             float* __restrict__ wc) {
    int blk = blockIdx.x;
    int tid = threadIdx.x;
    if (blk < NB_ZERO) {
        int i = (blk * 256 + tid) * 4;
        if (i < N_NODES) *(int4*)(cnt + i) = make_int4(0, 0, 0, 0);   // N_NODES % 4 == 0
    } else if (blk < NB_ZERO + NB_PACK) {
        // wpack[((nt*8+ks)*64+lane)*8 + j] = Wcat[ks*32 + (lane>>4)*8 + j][nt*16 + (lane&15)]
        int idx = (blk - NB_ZERO) * 256 + tid;   // 32768 total
        int j = idx & 7;
        int lane = (idx >> 3) & 63;
        int ks = (idx >> 9) & 7;
        int nt = idx >> 12;
        int krow = ks * 32 + ((lane >> 4) << 3) + j;
        int col = nt * 16 + (lane & 15);
        float v = (krow < 128) ? W1s[krow * 128 + col] : W1n[(krow - 128) * 128 + col];
        wpack[idx] = f2bf(v);
    } else {
        // wc[0..255]=Wcs[k][c], [256..511]=Wcn[k][c], [512..513]=bc
        int role = blk - NB_ZERO - NB_PACK;   // 0: Wcs, 1: Wcn + bc
        int k = tid >> 1, c = tid & 1;
        const float* W = role == 0 ? W2s : W2n;
        float s = 0.f;
        for (int j = 0; j < 128; ++j) s += W[k * 128 + j] * Wf[j * 2 + c];
        wc[role * 256 + k * 2 + c] = s;
        if (role == 1 && tid < 2) {
            float sb = bf[tid];
            for (int j = 0; j < 128; ++j) sb += b2[j] * Wf[j * 2 + tid];
            wc[512 + tid] = sb;
        }
    }
}

// ---------------- K1: XCD-sharded CSR build  ||  z = x@W1s + b1, y = x@W1n ----------------
__global__ __launch_bounds__(256) void k_main(const float* __restrict__ x,
                                              const int* __restrict__ src,
                                              const int* __restrict__ dst,
                                              const unsigned short* __restrict__ wpack,
                                              const float* __restrict__ b1,
                                              int* __restrict__ cnt,
                                              int* __restrict__ bucket,
                                              float* __restrict__ zbuf,
                                              unsigned short* __restrict__ yb) {
    int blk = blockIdx.x;
    int tid = threadIdx.x;

    if (blk < NB_BUILD) {
        // blk%8 tracks round-robin block->XCD (perf heuristic): one dst-range per XCD L2
        int shard = blk & 7;
        int chunk = blk >> 3;
        int lo = shard * SHARD_SZ;
        int hi = lo + SHARD_SZ;
        int base = chunk * CHUNK_EDGES;
        int4 d4[8], s4[8];
#pragma unroll
        for (int i = 0; i < 8; ++i) {            // all loads upfront -> 32 indep atomic chains
            int e0 = base + (i * 256 + tid) * 4;
            if (e0 < N_EDGES) {                  // N_EDGES % 4 == 0
                d4[i] = *(const int4*)(dst + e0);
                s4[i] = *(const int4*)(src + e0);
            } else {
                d4[i] = make_int4(-1, -1, -1, -1);
                s4[i] = make_int4(0, 0, 0, 0);
            }
        }
#pragma unroll
        for (int i = 0; i < 8; ++i) {
            int d, s, p;
            d = d4[i].x; s = s4[i].x;
            if (d >= lo && d < hi) { p = atomicAdd(&cnt[d], 1); if (p < CAP) bucket[(size_t)d * CAP + p] = s; }
            d = d4[i].y; s = s4[i].y;
            if (d >= lo && d < hi) { p = atomicAdd(&cnt[d], 1); if (p < CAP) bucket[(size_t)d * CAP + p] = s; }
            d = d4[i].z; s = s4[i].z;
            if (d >= lo && d < hi) { p = atomicAdd(&cnt[d], 1); if (p < CAP) bucket[(size_t)d * CAP + p] = s; }
            d = d4[i].w; s = s4[i].w;
            if (d >= lo && d < hi) { p = atomicAdd(&cnt[d], 1); if (p < CAP) bucket[(size_t)d * CAP + p] = s; }
        }
    } else {
        // ---- dense GEMMs on MFMA: graph-independent, hides under the atomic-bound build ----
        int g = blk - NB_BUILD;
        int wid = tid >> 6;
        int lane = tid & 63;
        int l15 = lane & 15;
        int rowBase = g * 64 + wid * 16;
        int arow = rowBase + l15;
        if (arow >= N_NODES) arow = N_NODES - 1;   // tail clamp; stores guarded
        int koff = (lane >> 4) << 3;

        const float* xrow = x + (size_t)arow * 128 + koff;
        bf16x8 a[4];
#pragma unroll
        for (int ks = 0; ks < 4; ++ks) {
            float4 f0 = *(const float4*)(xrow + ks * 32);
            float4 f1 = *(const float4*)(xrow + ks * 32 + 4);
            bf16x8 t;
            t[0] = (short)f2bf(f0.x); t[1] = (short)f2bf(f0.y);
            t[2] = (short)f2bf(f0.z); t[3] = (short)f2bf(f0.w);
            t[4] = (short)f2bf(f1.x); t[5] = (short)f2bf(f1.y);
            t[6] = (short)f2bf(f1.z); t[7] = (short)f2bf(f1.w);
            a[ks] = t;
        }

        f32x4 zacc[8] = {};
        f32x4 yacc[8] = {};
        const bf16x8* wp = (const bf16x8*)wpack + lane;
#pragma unroll
        for (int nt = 0; nt < 8; ++nt) {
#pragma unroll
            for (int ks = 0; ks < 4; ++ks)
                zacc[nt] = __builtin_amdgcn_mfma_f32_16x16x32_bf16(a[ks], wp[(nt * 8 + ks) * 64], zacc[nt], 0, 0, 0);
#pragma unroll
            for (int ks = 0; ks < 4; ++ks)
                yacc[nt] = __builtin_amdgcn_mfma_f32_16x16x32_bf16(a[ks], wp[(nt * 8 + 4 + ks) * 64], yacc[nt], 0, 0, 0);
        }

        // C/D layout: col = lane&15, row = (lane>>4)*4 + reg
        int crow0 = rowBase + ((lane >> 4) << 2);
#pragma unroll
        for (int nt = 0; nt < 8; ++nt) {
            int col = nt * 16 + l15;
            float bias = b1[col];
#pragma unroll
            for (int r = 0; r < 4; ++r) {
                int row = crow0 + r;
                if (row < N_NODES) {
                    zbuf[(size_t)row * 128 + col] = zacc[nt][r] + bias;
                    yb[(size_t)row * 128 + col] = f2bf(yacc[nt][r]);
                }
            }
        }
    }
}

// ---------------- K2: h1 = relu(z + mean_neigh(y)); pq = {h1@Wcs, h1@Wcn} ----------------
__global__ __launch_bounds__(256) void k_agg2(const unsigned short* __restrict__ yb,
                                              const float* __restrict__ zbuf,
                                              const int* __restrict__ cnt,
                                              const int* __restrict__ bucket,
                                              const float* __restrict__ wc,
                                              float* __restrict__ pq) {
    int blk = blockIdx.x;
    int wavein = threadIdx.x >> 6;
    int lane = threadIdx.x & 63;
    int nis = (blk >> 3) * 4 + wavein;          // node-in-shard
    if (nis >= SHARD_SZ) return;
    int node = (blk & 7) * SHARD_SZ + nis;      // contiguous node range per XCD -> L2-local bucket

    int deg = cnt[node];
    int n = deg < CAP ? deg : CAP;
    const int* bk = bucket + (size_t)node * CAP;
    float ax0 = 0.f, ay0 = 0.f, ax1 = 0.f, ay1 = 0.f;
    float ax2 = 0.f, ay2 = 0.f, ax3 = 0.f, ay3 = 0.f;
    int e = 0;
    for (; e + 16 <= n; e += 16) {
        int4 i0 = *(const int4*)(bk + e);
        int4 i1 = *(const int4*)(bk + e + 4);
        int4 i2 = *(const int4*)(bk + e + 8);
        int4 i3 = *(const int4*)(bk + e + 12);
        unsigned u0  = ((const unsigned*)(yb + (size_t)i0.x * 128))[lane];
        unsigned u1  = ((const unsigned*)(yb + (size_t)i0.y * 128))[lane];
        unsigned u2  = ((const unsigned*)(yb + (size_t)i0.z * 128))[lane];
        unsigned u3  = ((const unsigned*)(yb + (size_t)i0.w * 128))[lane];
        unsigned u4  = ((const unsigned*)(yb + (size_t)i1.x * 128))[lane];
        unsigned u5  = ((const unsigned*)(yb + (size_t)i1.y * 128))[lane];
        unsigned u6  = ((const unsigned*)(yb + (size_t)i1.z * 128))[lane];
        unsigned u7  = ((const unsigned*)(yb + (size_t)i1.w * 128))[lane];
        unsigned u8  = ((const unsigned*)(yb + (size_t)i2.x * 128))[lane];
        unsigned u9  = ((const unsigned*)(yb + (size_t)i2.y * 128))[lane];
        unsigned u10 = ((const unsigned*)(yb + (size_t)i2.z * 128))[lane];
        unsigned u11 = ((const unsigned*)(yb + (size_t)i2.w * 128))[lane];
        unsigned u12 = ((const unsigned*)(yb + (size_t)i3.x * 128))[lane];
        unsigned u13 = ((const unsigned*)(yb + (size_t)i3.y * 128))[lane];
        unsigned u14 = ((const unsigned*)(yb + (size_t)i3.z * 128))[lane];
        unsigned u15 = ((const unsigned*)(yb + (size_t)i3.w * 128))[lane];
        ax0 += bflo(u0);  ay0 += bfhi(u0);  ax1 += bflo(u1);  ay1 += bfhi(u1);
        ax2 += bflo(u2);  ay2 += bfhi(u2);  ax3 += bflo(u3);  ay3 += bfhi(u3);
        ax0 += bflo(u4);  ay0 += bfhi(u4);  ax1 += bflo(u5);  ay1 += bfhi(u5);
        ax2 += bflo(u6);  ay2 += bfhi(u6);  ax3 += bflo(u7);  ay3 += bfhi(u7);
        ax0 += bflo(u8);  ay0 += bfhi(u8);  ax1 += bflo(u9);  ay1 += bfhi(u9);
        ax2 += bflo(u10); ay2 += bfhi(u10); ax3 += bflo(u11); ay3 += bfhi(u11);
        ax0 += bflo(u12); ay0 += bfhi(u12); ax1 += bflo(u13); ay1 += bfhi(u13);
        ax2 += bflo(u14); ay2 += bfhi(u14); ax3 += bflo(u15); ay3 += bfhi(u15);
    }
    if (e + 8 <= n) {
        int4 i0 = *(const int4*)(bk + e);
        int4 i1 = *(const int4*)(bk + e + 4);
        unsigned u0 = ((const unsigned*)(yb + (size_t)i0.x * 128))[lane];
        unsigned u1 = ((const unsigned*)(yb + (size_t)i0.y * 128))[lane];
        unsigned u2 = ((const unsigned*)(yb + (size_t)i0.z * 128))[lane];
        unsigned u3 = ((const unsigned*)(yb + (size_t)i0.w * 128))[lane];
        unsigned u4 = ((const unsigned*)(yb + (size_t)i1.x * 128))[lane];
        unsigned u5 = ((const unsigned*)(yb + (size_t)i1.y * 128))[lane];
        unsigned u6 = ((const unsigned*)(yb + (size_t)i1.z * 128))[lane];
        unsigned u7 = ((const unsigned*)(yb + (size_t)i1.w * 128))[lane];
        ax0 += bflo(u0); ay0 += bfhi(u0); ax1 += bflo(u1); ay1 += bfhi(u1);
        ax2 += bflo(u2); ay2 += bfhi(u2); ax3 += bflo(u3); ay3 += bfhi(u3);
        ax0 += bflo(u4); ay0 += bfhi(u4); ax1 += bflo(u5); ay1 += bfhi(u5);
        ax2 += bflo(u6); ay2 += bfhi(u6); ax3 += bflo(u7); ay3 += bfhi(u7);
        e += 8;
    }
    if (e + 4 <= n) {
        int4 i0 = *(const int4*)(bk + e);
        unsigned u0 = ((const unsigned*)(yb + (size_t)i0.x * 128))[lane];
        unsigned u1 = ((const unsigned*)(yb + (size_t)i0.y * 128))[lane];
        unsigned u2 = ((const unsigned*)(yb + (size_t)i0.z * 128))[lane];
        unsigned u3 = ((const unsigned*)(yb + (size_t)i0.w * 128))[lane];
        ax0 += bflo(u0); ay0 += bfhi(u0); ax1 += bflo(u1); ay1 += bfhi(u1);
        ax2 += bflo(u2); ay2 += bfhi(u2); ax3 += bflo(u3); ay3 += bfhi(u3);
        e += 4;
    }
    for (; e < n; ++e) {
        unsigned u = ((const unsigned*)(yb + (size_t)bk[e] * 128))[lane];
        ax0 += bflo(u); ay0 += bfhi(u);
    }
    float inv = 1.0f / fmaxf((float)deg, 1.0f);
    float mx = ((ax0 + ax1) + (ax2 + ax3)) * inv;
    float my = ((ay0 + ay1) + (ay2 + ay3)) * inv;

    float2 zv = ((const float2*)(zbuf + (size_t)node * 128))[lane];
    float h0 = fmaxf(zv.x + mx, 0.f);
    float h1v = fmaxf(zv.y + my, 0.f);

    float2 ws0 = ((const float2*)wc)[2 * lane];
    float2 ws1 = ((const float2*)wc)[2 * lane + 1];
    float2 wn0 = ((const float2*)(wc + 256))[2 * lane];
    float2 wn1 = ((const float2*)(wc + 256))[2 * lane + 1];
    float p0 = h0 * ws0.x + h1v * ws1.x;
    float p1 = h0 * ws0.y + h1v * ws1.y;
    float q0 = h0 * wn0.x + h1v * wn1.x;
    float q1 = h0 * wn0.y + h1v * wn1.y;
#pragma unroll
    for (int off = 32; off >= 1; off >>= 1) {
        p0 += __shfl_xor(p0, off, 64);
        p1 += __shfl_xor(p1, off, 64);
        q0 += __shfl_xor(q0, off, 64);
        q1 += __shfl_xor(q1, off, 64);
    }
    if (lane == 0) {
        float4 o; o.x = p0; o.y = p1; o.z = q0; o.w = q1;
        ((float4*)pq)[node] = o;
    }
}

// ---------------- K3: out[n] = pq[n].p + mean_src(pq[src].q) + bc ----------------
__global__ __launch_bounds__(256) void k_final(const float* __restrict__ pq,
                                               const int* __restrict__ cnt,
                                               const int* __restrict__ bucket,
                                               const float* __restrict__ wc,
                                               float* __restrict__ out) {
    int blk = blockIdx.x;
    int wavein = threadIdx.x >> 6;
    int lane = threadIdx.x & 63;
    int nis = (blk >> 3) * 4 + wavein;
    if (nis >= SHARD_SZ) return;
    int node = (blk & 7) * SHARD_SZ + nis;

    int deg = cnt[node];
    int n = deg < CAP ? deg : CAP;
    float qx = 0.f, qy = 0.f;
    if (lane < n) {
        int s = bucket[(size_t)node * CAP + lane];
        float2 q = *(const float2*)(pq + (size_t)s * 4 + 2);
        qx = q.x; qy = q.y;
    }
#pragma unroll
    for (int off = 32; off >= 1; off >>= 1) {
        qx += __shfl_xor(qx, off, 64);
        qy += __shfl_xor(qy, off, 64);
    }
    if (lane == 0) {
        float inv = 1.0f / fmaxf((float)deg, 1.0f);
        float2 p = *(const float2*)(pq + (size_t)node * 4);
        out[(size_t)node * 2 + 0] = p.x + qx * inv + wc[512];
        out[(size_t)node * 2 + 1] = p.y + qy * inv + wc[513];
    }
}

extern "C" void kernel_launch(void* const* d_in, const int* in_sizes, int n_in,
                              void* d_out, int out_size, void* d_ws, size_t ws_size,
                              hipStream_t stream) {
    const float* x   = (const float*)d_in[0];
    const int* esrc  = (const int*)d_in[1];
    const int* edst  = (const int*)d_in[2];
    const float* W1s = (const float*)d_in[3];
    const float* W1n = (const float*)d_in[4];
    const float* b1  = (const float*)d_in[5];
    const float* W2s = (const float*)d_in[6];
    const float* W2n = (const float*)d_in[7];
    const float* b2  = (const float*)d_in[8];
    const float* Wf  = (const float*)d_in[9];
    const float* bf  = (const float*)d_in[10];
    float* out = (float*)d_out;

    char* ws = (char*)d_ws;
    auto alloc = [&](size_t bytes) {
        char* p = ws;
        ws += (bytes + 255) & ~(size_t)255;
        return p;
    };
    int*            cnt    = (int*)           alloc((size_t)N_NODES * 4);
    int*            bucket = (int*)           alloc((size_t)N_NODES * CAP * 4);
    float*          zbuf   = (float*)         alloc((size_t)N_NODES * 128 * 4);
    unsigned short* yb     = (unsigned short*)alloc((size_t)N_NODES * 128 * 2);
    float*          pq     = (float*)         alloc((size_t)N_NODES * 4 * 4);
    unsigned short* wpack  = (unsigned short*)alloc(8 * 8 * 64 * 8 * 2);
    float*          wc     = (float*)         alloc(1024 * 4);

    k_pre<<<NB_PRE, 256, 0, stream>>>(W1s, W1n, W2s, W2n, b2, Wf, bf, cnt, wpack, wc);
    k_main<<<NB_MAIN, 256, 0, stream>>>(x, esrc, edst, wpack, b1, cnt, bucket, zbuf, yb);
    k_agg2<<<NB_AGG, 256, 0, stream>>>(yb, zbuf, cnt, bucket, wc, pq);
    k_final<<<NB_AGG, 256, 0, stream>>>(pq, cnt, bucket, wc, out);
}

// Round 7
// 115.718 us; speedup vs baseline: 1.2154x; 1.2154x over previous
//
#include <hip/hip_runtime.h>
#include <cstdint>
#include <cstddef>

#define N_NODES 50000
#define N_EDGES 800000
#define CAP 64        // max in-degree capacity; Poisson(16): P(>64) astronomically small

// XCD-sharded build geometry
#define SHARDS 8
#define SHARD_SZ 6250                 // N_NODES / SHARDS
#define CHUNK_EDGES 4096              // 256 thr * 4 edges * 4 iters
#define N_CHUNKS 196                  // 196*4096 = 802816 >= 800000
#define NB_BUILD (N_CHUNKS * SHARDS)  // 1568

// K0 (pre) block ranges: zero cnt | pack W | combine
#define NB_ZERO 49                    // 49 * 1024 ints >= 50000
#define NB_PACK 128
#define NB_COMB 2
#define NB_PRE  (NB_ZERO + NB_PACK + NB_COMB)

// K1 (main): groups of 16 blocks = 8 build (shard 0..7 -> XCD 0..7) + 8 gemm
#define NB_GEMM 782                   // ceil(50000/64) row-tiles per role (Z and Y)
#define NB_MAIN (N_CHUNKS * 16)       // 3136; gemm slots 1568 >= 2*782

// K2/K3 node remap: 1563 blocks per shard (4 nodes per block)
#define NB_AGG (1563 * 8)

typedef __attribute__((ext_vector_type(8))) short bf16x8;   // MFMA A/B frag (4 VGPRs)
typedef __attribute__((ext_vector_type(4))) float f32x4;    // MFMA C/D frag

__device__ __forceinline__ unsigned short f2bf(float f) {
    unsigned u = __builtin_bit_cast(unsigned, f);
    u += 0x7fff + ((u >> 16) & 1);          // round-to-nearest-even
    return (unsigned short)(u >> 16);
}
__device__ __forceinline__ float bflo(unsigned u) { return __builtin_bit_cast(float, u << 16); }
__device__ __forceinline__ float bfhi(unsigned u) { return __builtin_bit_cast(float, u & 0xffff0000u); }

// ---------------- K0: zero cnt | pack [W1s;W1n] -> bf16 frags | fold W2*@Wf ----------------
__global__ __launch_bounds__(256) void k_pre(const float* __restrict__ W1s,
                                             const float* __restrict__ W1n,
                                             const float* __restrict__ W2s,
                                             const float* __restrict__ W2n,
                                             const float* __restrict__ b2,
                                             const float* __restrict__ Wf,
                                             const float* __restrict__ bf,
                                             int* __restrict__ cnt,
                                             unsigned short* __restrict__ wpack,
                                             float* __restrict__ wc) {
    int blk = blockIdx.x;
    int tid = threadIdx.x;
    if (blk < NB_ZERO) {
        int i = (blk * 256 + tid) * 4;
        if (i < N_NODES) *(int4*)(cnt + i) = make_int4(0, 0, 0, 0);   // N_NODES % 4 == 0
    } else if (blk < NB_ZERO + NB_PACK) {
        // wpack[((nt*8+ks)*64+lane)*8 + j] = Wcat[ks*32 + (lane>>4)*8 + j][nt*16 + (lane&15)]
        int idx = (blk - NB_ZERO) * 256 + tid;   // 32768 total
        int j = idx & 7;
        int lane = (idx >> 3) & 63;
        int ks = (idx >> 9) & 7;
        int nt = idx >> 12;
        int krow = ks * 32 + ((lane >> 4) << 3) + j;
        int col = nt * 16 + (lane & 15);
        float v = (krow < 128) ? W1s[krow * 128 + col] : W1n[(krow - 128) * 128 + col];
        wpack[idx] = f2bf(v);
    } else {
        // wc[0..255]=Wcs[k][c], [256..511]=Wcn[k][c], [512..513]=bc
        int role = blk - NB_ZERO - NB_PACK;   // 0: Wcs, 1: Wcn + bc
        int k = tid >> 1, c = tid & 1;
        const float* W = role == 0 ? W2s : W2n;
        float s = 0.f;
        for (int j = 0; j < 128; ++j) s += W[k * 128 + j] * Wf[j * 2 + c];
        wc[role * 256 + k * 2 + c] = s;
        if (role == 1 && tid < 2) {
            float sb = bf[tid];
            for (int j = 0; j < 128; ++j) sb += b2[j] * Wf[j * 2 + tid];
            wc[512 + tid] = sb;
        }
    }
}

// ---------------- K1: interleaved {XCD-sharded CSR build} || {z = x@W1s+b1, y = x@W1n} ----------------
__global__ __launch_bounds__(256) void k_main(const float* __restrict__ x,
                                              const int* __restrict__ src,
                                              const int* __restrict__ dst,
                                              const unsigned short* __restrict__ wpack,
                                              const float* __restrict__ b1,
                                              int* __restrict__ cnt,
                                              unsigned short* __restrict__ bucket,
                                              unsigned short* __restrict__ zb,
                                              unsigned short* __restrict__ yb) {
    int blk = blockIdx.x;
    int tid = threadIdx.x;
    int pos = blk & 15;          // group-of-16 interleave: 0..7 build, 8..15 gemm
    int group = blk >> 4;

    if (pos < 8) {
        // ---- build: shard = pos; with blk%8 == pos, all blocks of shard s land on XCD s ----
        int shard = pos;
        int lo = shard * SHARD_SZ;
        int hi = lo + SHARD_SZ;
        int base = group * CHUNK_EDGES;
#pragma unroll
        for (int i = 0; i < CHUNK_EDGES / 1024; ++i) {
            int e0 = base + (i * 256 + tid) * 4;
            if (e0 >= N_EDGES) break;                    // N_EDGES % 4 == 0
            int4 d4 = *(const int4*)(dst + e0);
            int4 s4 = *(const int4*)(src + e0);
            if (d4.x >= lo && d4.x < hi) { int p = atomicAdd(&cnt[d4.x], 1); if (p < CAP) bucket[(size_t)d4.x * CAP + p] = (unsigned short)s4.x; }
            if (d4.y >= lo && d4.y < hi) { int p = atomicAdd(&cnt[d4.y], 1); if (p < CAP) bucket[(size_t)d4.y * CAP + p] = (unsigned short)s4.y; }
            if (d4.z >= lo && d4.z < hi) { int p = atomicAdd(&cnt[d4.z], 1); if (p < CAP) bucket[(size_t)d4.z * CAP + p] = (unsigned short)s4.z; }
            if (d4.w >= lo && d4.w < hi) { int p = atomicAdd(&cnt[d4.w], 1); if (p < CAP) bucket[(size_t)d4.w * CAP + p] = (unsigned short)s4.w; }
        }
    } else {
        // ---- dense GEMM role blocks: g even -> z = x@W1s + b1, g odd -> y = x@W1n ----
        int g = group * 8 + (pos - 8);
        int grow = g >> 1;
        if (grow >= NB_GEMM) return;
        int isY = g & 1;
        int wid = tid >> 6;
        int lane = tid & 63;
        int l15 = lane & 15;
        int rowBase = grow * 64 + wid * 16;
        int arow = rowBase + l15;
        if (arow >= N_NODES) arow = N_NODES - 1;   // tail clamp; stores guarded
        int koff = (lane >> 4) << 3;

        const float* xrow = x + (size_t)arow * 128 + koff;
        bf16x8 a[4];
#pragma unroll
        for (int ks = 0; ks < 4; ++ks) {
            float4 f0 = *(const float4*)(xrow + ks * 32);
            float4 f1 = *(const float4*)(xrow + ks * 32 + 4);
            bf16x8 t;
            t[0] = (short)f2bf(f0.x); t[1] = (short)f2bf(f0.y);
            t[2] = (short)f2bf(f0.z); t[3] = (short)f2bf(f0.w);
            t[4] = (short)f2bf(f1.x); t[5] = (short)f2bf(f1.y);
            t[6] = (short)f2bf(f1.z); t[7] = (short)f2bf(f1.w);
            a[ks] = t;
        }

        f32x4 acc[8] = {};
        const bf16x8* wp = (const bf16x8*)wpack + lane + (size_t)isY * 4 * 64;  // ks offset 4 for W1n
#pragma unroll
        for (int nt = 0; nt < 8; ++nt) {
#pragma unroll
            for (int ks = 0; ks < 4; ++ks)
                acc[nt] = __builtin_amdgcn_mfma_f32_16x16x32_bf16(a[ks], wp[(nt * 8 + ks) * 64], acc[nt], 0, 0, 0);
        }

        // C/D layout: col = lane&15, row = (lane>>4)*4 + reg
        unsigned short* outb = isY ? yb : zb;
        int crow0 = rowBase + ((lane >> 4) << 2);
#pragma unroll
        for (int nt = 0; nt < 8; ++nt) {
            int col = nt * 16 + l15;
            float bias = isY ? 0.f : b1[col];
#pragma unroll
            for (int r = 0; r < 4; ++r) {
                int row = crow0 + r;
                if (row < N_NODES) outb[(size_t)row * 128 + col] = f2bf(acc[nt][r] + bias);
            }
        }
    }
}

// ---------------- K2: h1 = relu(z + mean_neigh(y)); pq = {h1@Wcs, h1@Wcn} ----------------
__global__ __launch_bounds__(256) void k_agg2(const unsigned short* __restrict__ yb,
                                              const unsigned short* __restrict__ zb,
                                              const int* __restrict__ cnt,
                                              const unsigned short* __restrict__ bucket,
                                              const float* __restrict__ wc,
                                              float* __restrict__ pq) {
    int blk = blockIdx.x;
    int wavein = threadIdx.x >> 6;
    int lane = threadIdx.x & 63;
    int nis = (blk >> 3) * 4 + wavein;          // node-in-shard
    if (nis >= SHARD_SZ) return;
    int node = (blk & 7) * SHARD_SZ + nis;      // shard s nodes read from XCD-s-local bucket

    int deg = cnt[node];
    int n = deg < CAP ? deg : CAP;
    const unsigned short* bk = bucket + (size_t)node * CAP;
    float ax0 = 0.f, ay0 = 0.f, ax1 = 0.f, ay1 = 0.f;
    float ax2 = 0.f, ay2 = 0.f, ax3 = 0.f, ay3 = 0.f;
    int e = 0;
    for (; e + 16 <= n; e += 16) {
        uint4 ia = *(const uint4*)(bk + e);       // 8 packed ushort indices
        uint4 ib = *(const uint4*)(bk + e + 8);
        int s0  = ia.x & 0xffff, s1  = ia.x >> 16, s2  = ia.y & 0xffff, s3  = ia.y >> 16;
        int s4  = ia.z & 0xffff, s5  = ia.z >> 16, s6  = ia.w & 0xffff, s7  = ia.w >> 16;
        int s8  = ib.x & 0xffff, s9  = ib.x >> 16, s10 = ib.y & 0xffff, s11 = ib.y >> 16;
        int s12 = ib.z & 0xffff, s13 = ib.z >> 16, s14 = ib.w & 0xffff, s15 = ib.w >> 16;
        unsigned u0  = ((const unsigned*)(yb + (size_t)s0  * 128))[lane];
        unsigned u1  = ((const unsigned*)(yb + (size_t)s1  * 128))[lane];
        unsigned u2  = ((const unsigned*)(yb + (size_t)s2  * 128))[lane];
        unsigned u3  = ((const unsigned*)(yb + (size_t)s3  * 128))[lane];
        unsigned u4  = ((const unsigned*)(yb + (size_t)s4  * 128))[lane];
        unsigned u5  = ((const unsigned*)(yb + (size_t)s5  * 128))[lane];
        unsigned u6  = ((const unsigned*)(yb + (size_t)s6  * 128))[lane];
        unsigned u7  = ((const unsigned*)(yb + (size_t)s7  * 128))[lane];
        unsigned u8  = ((const unsigned*)(yb + (size_t)s8  * 128))[lane];
        unsigned u9  = ((const unsigned*)(yb + (size_t)s9  * 128))[lane];
        unsigned u10 = ((const unsigned*)(yb + (size_t)s10 * 128))[lane];
        unsigned u11 = ((const unsigned*)(yb + (size_t)s11 * 128))[lane];
        unsigned u12 = ((const unsigned*)(yb + (size_t)s12 * 128))[lane];
        unsigned u13 = ((const unsigned*)(yb + (size_t)s13 * 128))[lane];
        unsigned u14 = ((const unsigned*)(yb + (size_t)s14 * 128))[lane];
        unsigned u15 = ((const unsigned*)(yb + (size_t)s15 * 128))[lane];
        ax0 += bflo(u0);  ay0 += bfhi(u0);  ax1 += bflo(u1);  ay1 += bfhi(u1);
        ax2 += bflo(u2);  ay2 += bfhi(u2);  ax3 += bflo(u3);  ay3 += bfhi(u3);
        ax0 += bflo(u4);  ay0 += bfhi(u4);  ax1 += bflo(u5);  ay1 += bfhi(u5);
        ax2 += bflo(u6);  ay2 += bfhi(u6);  ax3 += bflo(u7);  ay3 += bfhi(u7);
        ax0 += bflo(u8);  ay0 += bfhi(u8);  ax1 += bflo(u9);  ay1 += bfhi(u9);
        ax2 += bflo(u10); ay2 += bfhi(u10); ax3 += bflo(u11); ay3 += bfhi(u11);
        ax0 += bflo(u12); ay0 += bfhi(u12); ax1 += bflo(u13); ay1 += bfhi(u13);
        ax2 += bflo(u14); ay2 += bfhi(u14); ax3 += bflo(u15); ay3 += bfhi(u15);
    }
    if (e + 8 <= n) {
        uint4 ia = *(const uint4*)(bk + e);
        int s0 = ia.x & 0xffff, s1 = ia.x >> 16, s2 = ia.y & 0xffff, s3 = ia.y >> 16;
        int s4 = ia.z & 0xffff, s5 = ia.z >> 16, s6 = ia.w & 0xffff, s7 = ia.w >> 16;
        unsigned u0 = ((const unsigned*)(yb + (size_t)s0 * 128))[lane];
        unsigned u1 = ((const unsigned*)(yb + (size_t)s1 * 128))[lane];
        unsigned u2 = ((const unsigned*)(yb + (size_t)s2 * 128))[lane];
        unsigned u3 = ((const unsigned*)(yb + (size_t)s3 * 128))[lane];
        unsigned u4 = ((const unsigned*)(yb + (size_t)s4 * 128))[lane];
        unsigned u5 = ((const unsigned*)(yb + (size_t)s5 * 128))[lane];
        unsigned u6 = ((const unsigned*)(yb + (size_t)s6 * 128))[lane];
        unsigned u7 = ((const unsigned*)(yb + (size_t)s7 * 128))[lane];
        ax0 += bflo(u0); ay0 += bfhi(u0); ax1 += bflo(u1); ay1 += bfhi(u1);
        ax2 += bflo(u2); ay2 += bfhi(u2); ax3 += bflo(u3); ay3 += bfhi(u3);
        ax0 += bflo(u4); ay0 += bfhi(u4); ax1 += bflo(u5); ay1 += bfhi(u5);
        ax2 += bflo(u6); ay2 += bfhi(u6); ax3 += bflo(u7); ay3 += bfhi(u7);
        e += 8;
    }
    if (e + 4 <= n) {
        uint2 ia = *(const uint2*)(bk + e);
        int s0 = ia.x & 0xffff, s1 = ia.x >> 16, s2 = ia.y & 0xffff, s3 = ia.y >> 16;
        unsigned u0 = ((const unsigned*)(yb + (size_t)s0 * 128))[lane];
        unsigned u1 = ((const unsigned*)(yb + (size_t)s1 * 128))[lane];
        unsigned u2 = ((const unsigned*)(yb + (size_t)s2 * 128))[lane];
        unsigned u3 = ((const unsigned*)(yb + (size_t)s3 * 128))[lane];
        ax0 += bflo(u0); ay0 += bfhi(u0); ax1 += bflo(u1); ay1 += bfhi(u1);
        ax2 += bflo(u2); ay2 += bfhi(u2); ax3 += bflo(u3); ay3 += bfhi(u3);
        e += 4;
    }
    for (; e < n; ++e) {
        unsigned u = ((const unsigned*)(yb + (size_t)bk[e] * 128))[lane];
        ax0 += bflo(u); ay0 += bfhi(u);
    }
    float inv = 1.0f / fmaxf((float)deg, 1.0f);
    float mx = ((ax0 + ax1) + (ax2 + ax3)) * inv;
    float my = ((ay0 + ay1) + (ay2 + ay3)) * inv;

    unsigned zu = ((const unsigned*)(zb + (size_t)node * 128))[lane];
    float h0 = fmaxf(bflo(zu) + mx, 0.f);
    float h1v = fmaxf(bfhi(zu) + my, 0.f);

    float2 ws0 = ((const float2*)wc)[2 * lane];
    float2 ws1 = ((const float2*)wc)[2 * lane + 1];
    float2 wn0 = ((const float2*)(wc + 256))[2 * lane];
    float2 wn1 = ((const float2*)(wc + 256))[2 * lane + 1];
    float p0 = h0 * ws0.x + h1v * ws1.x;
    float p1 = h0 * ws0.y + h1v * ws1.y;
    float q0 = h0 * wn0.x + h1v * wn1.x;
    float q1 = h0 * wn0.y + h1v * wn1.y;
#pragma unroll
    for (int off = 32; off >= 1; off >>= 1) {
        p0 += __shfl_xor(p0, off, 64);
        p1 += __shfl_xor(p1, off, 64);
        q0 += __shfl_xor(q0, off, 64);
        q1 += __shfl_xor(q1, off, 64);
    }
    if (lane == 0) {
        float4 o; o.x = p0; o.y = p1; o.z = q0; o.w = q1;
        ((float4*)pq)[node] = o;
    }
}

// ---------------- K3: out[n] = pq[n].p + mean_src(pq[src].q) + bc ----------------
__global__ __launch_bounds__(256) void k_final(const float* __restrict__ pq,
                                               const int* __restrict__ cnt,
                                               const unsigned short* __restrict__ bucket,
                                               const float* __restrict__ wc,
                                               float* __restrict__ out) {
    int blk = blockIdx.x;
    int wavein = threadIdx.x >> 6;
    int lane = threadIdx.x & 63;
    int nis = (blk >> 3) * 4 + wavein;
    if (nis >= SHARD_SZ) return;
    int node = (blk & 7) * SHARD_SZ + nis;

    int deg = cnt[node];
    int n = deg < CAP ? deg : CAP;
    float qx = 0.f, qy = 0.f;
    if (lane < n) {
        int s = bucket[(size_t)node * CAP + lane];
        float2 q = *(const float2*)(pq + (size_t)s * 4 + 2);
        qx = q.x; qy = q.y;
    }
#pragma unroll
    for (int off = 32; off >= 1; off >>= 1) {
        qx += __shfl_xor(qx, off, 64);
        qy += __shfl_xor(qy, off, 64);
    }
    if (lane == 0) {
        float inv = 1.0f / fmaxf((float)deg, 1.0f);
        float2 p = *(const float2*)(pq + (size_t)node * 4);
        out[(size_t)node * 2 + 0] = p.x + qx * inv + wc[512];
        out[(size_t)node * 2 + 1] = p.y + qy * inv + wc[513];
    }
}

extern "C" void kernel_launch(void* const* d_in, const int* in_sizes, int n_in,
                              void* d_out, int out_size, void* d_ws, size_t ws_size,
                              hipStream_t stream) {
    const float* x   = (const float*)d_in[0];
    const int* esrc  = (const int*)d_in[1];
    const int* edst  = (const int*)d_in[2];
    const float* W1s = (const float*)d_in[3];
    const float* W1n = (const float*)d_in[4];
    const float* b1  = (const float*)d_in[5];
    const float* W2s = (const float*)d_in[6];
    const float* W2n = (const float*)d_in[7];
    const float* b2  = (const float*)d_in[8];
    const float* Wf  = (const float*)d_in[9];
    const float* bf  = (const float*)d_in[10];
    float* out = (float*)d_out;

    char* ws = (char*)d_ws;
    auto alloc = [&](size_t bytes) {
        char* p = ws;
        ws += (bytes + 255) & ~(size_t)255;
        return p;
    };
    int*            cnt    = (int*)           alloc((size_t)N_NODES * 4);
    unsigned short* bucket = (unsigned short*)alloc((size_t)N_NODES * CAP * 2);
    unsigned short* zb     = (unsigned short*)alloc((size_t)N_NODES * 128 * 2);
    unsigned short* yb     = (unsigned short*)alloc((size_t)N_NODES * 128 * 2);
    float*          pq     = (float*)         alloc((size_t)N_NODES * 4 * 4);
    unsigned short* wpack  = (unsigned short*)alloc(8 * 8 * 64 * 8 * 2);
    float*          wc     = (float*)         alloc(1024 * 4);

    k_pre<<<NB_PRE, 256, 0, stream>>>(W1s, W1n, W2s, W2n, b2, Wf, bf, cnt, wpack, wc);
    k_main<<<NB_MAIN, 256, 0, stream>>>(x, esrc, edst, wpack, b1, cnt, bucket, zb, yb);
    k_agg2<<<NB_AGG, 256, 0, stream>>>(yb, zb, cnt, bucket, wc, pq);
    k_final<<<NB_AGG, 256, 0, stream>>>(pq, cnt, bucket, wc, out);
}